// Round 5
// baseline (2652.318 us; speedup 1.0000x reference)
//
#include <hip/hip_runtime.h>

#define N_NODES 100000
#define N_EDGES 600000
#define NGRAPH 512
#define NOPS_T 8
#define EPS_MSG 1e-7f
#define EPS_LN 1e-5f

typedef unsigned short u16;
typedef unsigned int u32;
typedef __attribute__((ext_vector_type(8))) short short8;   // 8 bf16 (4 VGPRs) MFMA A/B frag
typedef __attribute__((ext_vector_type(4))) float f32x4;    // MFMA C/D frag

__device__ __forceinline__ float bf2f(u16 u) {
    union { float f; u32 i; } v; v.i = ((u32)u) << 16; return v.f;
}
__device__ __forceinline__ u16 f2bf(float f) {
    union { float f; u32 i; } v; v.f = f;
    u32 r = (v.i + 0x7fffu + ((v.i >> 16) & 1u)) >> 16;   // RNE
    return (u16)r;
}
__device__ __forceinline__ float wave_sum(float v) {
    #pragma unroll
    for (int off = 32; off > 0; off >>= 1) v += __shfl_xor(v, off, 64);
    return v;
}

// =============== prep: bf16 transposed weights (n-major, k contiguous) ===============
// tW1[l][n*128+k] = bf16(W1[l][k*256+n]);  tW2[l][n*256+k] = bf16(W2[l][k*128+n])
__global__ __launch_bounds__(256) void k_prep(const float* __restrict__ W1,
                                              const float* __restrict__ W2,
                                              u16* __restrict__ tW1,
                                              u16* __restrict__ tW2) {
    int i = blockIdx.x * 256 + threadIdx.x;   // over 4*32768
    if (i >= 4 * 32768) return;
    int l = i >> 15, r = i & 32767;
    int n1 = r >> 7, k1 = r & 127;
    tW1[i] = f2bf(W1[(l << 15) + k1 * 256 + n1]);
    int n2 = r >> 8, k2 = r & 255;
    tW2[i] = f2bf(W2[(l << 15) + k2 * 128 + n2]);
}

// =============== encoder: h2 = bf16(x @ We + be) ===============
__global__ __launch_bounds__(256, 1) void k_enc(const float* __restrict__ x,
                                                const float* __restrict__ We,
                                                const float* __restrict__ be,
                                                u16* __restrict__ h2) {
    __shared__ __align__(16) u16 sWe[128 * 136];   // We^T padded (+8): row n, k contiguous
    __shared__ float sB[128];
    int tid = threadIdx.x;
    for (int i = tid; i < 128 * 128; i += 256) { int k = i >> 7, n = i & 127; sWe[n * 136 + k] = f2bf(We[i]); }
    if (tid < 128) sB[tid] = be[tid];
    __syncthreads();
    int wave = tid >> 6, lane = tid & 63, q = lane >> 4, c = lane & 15;
    for (int tile = blockIdx.x * 4 + wave; tile < N_NODES / 16; tile += gridDim.x * 4) {
        int n0 = tile * 16;
        const float4* xp = (const float4*)(x + (size_t)(n0 + c) * 128);
        short8 af[4];
        #pragma unroll
        for (int ks = 0; ks < 4; ks++) {
            float4 v0 = xp[ks * 8 + q * 2], v1 = xp[ks * 8 + q * 2 + 1];
            short8 a;
            a[0] = (short)f2bf(v0.x); a[1] = (short)f2bf(v0.y);
            a[2] = (short)f2bf(v0.z); a[3] = (short)f2bf(v0.w);
            a[4] = (short)f2bf(v1.x); a[5] = (short)f2bf(v1.y);
            a[6] = (short)f2bf(v1.z); a[7] = (short)f2bf(v1.w);
            af[ks] = a;
        }
        f32x4 acc[8];
        #pragma unroll
        for (int t = 0; t < 8; t++) {
            f32x4 a4 = {0.f, 0.f, 0.f, 0.f};
            const short8* bp = (const short8*)(sWe + (t * 16 + c) * 136);
            #pragma unroll
            for (int ks = 0; ks < 4; ks++)
                a4 = __builtin_amdgcn_mfma_f32_16x16x32_bf16(af[ks], bp[ks * 4 + q], a4, 0, 0, 0);
            acc[t] = a4;
        }
        u16* h2b = h2 + (size_t)n0 * 128;
        #pragma unroll
        for (int t = 0; t < 8; t++)
            #pragma unroll
            for (int i = 0; i < 4; i++) {
                int idx = (q * 4 + i) * 128 + t * 16 + c;     // D: row=q*4+i, col=t*16+c
                h2b[idx] = f2bf(acc[t][i] + sB[t * 16 + c]);
            }
    }
}

// =============== CSR build (once per launch; edges static across layers) ===============
__global__ __launch_bounds__(256) void k_hist(const int* __restrict__ ei, int* __restrict__ deg) {
    int e = blockIdx.x * 256 + threadIdx.x;
    if (e < N_EDGES) atomicAdd(&deg[ei[N_EDGES + e]], 1);
}

__global__ __launch_bounds__(256) void k_scan1(const int* __restrict__ deg,
                                               int* __restrict__ offs,
                                               int* __restrict__ bsum) {
    __shared__ int swv[4];
    int b = blockIdx.x, t = threadIdx.x;
    int base = b * 1024 + t * 4;
    int4 v = {0, 0, 0, 0};
    if (base < N_NODES) v = *(const int4*)(deg + base);   // N_NODES % 4 == 0
    int s = v.x + v.y + v.z + v.w;
    int lane = t & 63, wid = t >> 6;
    int incl = s;
    #pragma unroll
    for (int off = 1; off < 64; off <<= 1) {
        int o = __shfl_up(incl, off, 64);
        if (lane >= off) incl += o;
    }
    if (lane == 63) swv[wid] = incl;
    __syncthreads();
    int wbase = 0;
    #pragma unroll
    for (int w = 0; w < 4; w++) if (w < wid) wbase += swv[w];
    int ex = wbase + incl - s;
    if (base < N_NODES) {
        offs[base]     = ex;
        offs[base + 1] = ex + v.x;
        offs[base + 2] = ex + v.x + v.y;
        offs[base + 3] = ex + v.x + v.y + v.z;
    }
    if (t == 255) bsum[b] = wbase + incl;
}

__global__ __launch_bounds__(128) void k_scan2(int* __restrict__ bsum, int nb) {
    __shared__ int s[128];
    int t = threadIdx.x;
    int v = t < nb ? bsum[t] : 0;
    s[t] = v;
    __syncthreads();
    for (int off = 1; off < 128; off <<= 1) {
        int a = t >= off ? s[t - off] : 0;
        __syncthreads();
        s[t] += a;
        __syncthreads();
    }
    if (t < nb) bsum[t] = s[t] - v;
}

__global__ __launch_bounds__(256) void k_scan3(int* __restrict__ offs,
                                               const int* __restrict__ bsum,
                                               int* __restrict__ cursor) {
    int b = blockIdx.x, t = threadIdx.x;
    int base = b * 1024 + t * 4;
    if (base >= N_NODES) return;
    int add = bsum[b];
    #pragma unroll
    for (int i = 0; i < 4; i++) {
        int o = offs[base + i] + add;
        offs[base + i] = o;
        cursor[base + i] = o;
    }
}

__global__ __launch_bounds__(256) void k_scatter(const int* __restrict__ ei,
                                                 const int* __restrict__ ea,
                                                 int* __restrict__ cursor,
                                                 int* __restrict__ csr) {
    int e = blockIdx.x * 256 + threadIdx.x;
    if (e >= N_EDGES) return;
    int s = ei[e], d = ei[N_EDGES + e], a = ea[e];
    int pos = atomicAdd(&cursor[d], 1);
    csr[pos] = s | (a << 24);                 // src < 2^17, attr < 8
}

// =============== aggregate (gather, no atomics): xin = bf16(h2 + sum msgs) ===============
__global__ __launch_bounds__(256) void k_agg(const int* __restrict__ offs,
                                             const int* __restrict__ deg,
                                             const int* __restrict__ csr,
                                             const float* __restrict__ Et,
                                             const u16* __restrict__ h2,
                                             u16* __restrict__ xin) {
    __shared__ float4 sE[NOPS_T * 32];
    int tid = threadIdx.x;
    sE[tid] = ((const float4*)Et)[tid];
    __syncthreads();
    int n = blockIdx.x * 8 + (tid >> 5);
    if (n >= N_NODES) return;
    int g = tid & 31;
    float a0 = 0.f, a1 = 0.f, a2 = 0.f, a3 = 0.f;
    int st = offs[n], dg = deg[n];
    for (int j = 0; j < dg; j++) {
        int p = csr[st + j];
        int s = p & 0xFFFFFF;
        int a = ((u32)p) >> 24;
        uint2 hv = *(const uint2*)(h2 + (size_t)s * 128 + g * 4);
        float4 ev = sE[a * 32 + g];
        a0 += fmaxf(bf2f((u16)(hv.x & 0xffff)) + ev.x, 0.f) + EPS_MSG;
        a1 += fmaxf(bf2f((u16)(hv.x >> 16))    + ev.y, 0.f) + EPS_MSG;
        a2 += fmaxf(bf2f((u16)(hv.y & 0xffff)) + ev.z, 0.f) + EPS_MSG;
        a3 += fmaxf(bf2f((u16)(hv.y >> 16))    + ev.w, 0.f) + EPS_MSG;
    }
    uint2 hd = *(const uint2*)(h2 + (size_t)n * 128 + g * 4);
    u32 o0 = (u32)f2bf(bf2f((u16)(hd.x & 0xffff)) + a0) |
             ((u32)f2bf(bf2f((u16)(hd.x >> 16))   + a1) << 16);
    u32 o1 = (u32)f2bf(bf2f((u16)(hd.y & 0xffff)) + a2) |
             ((u32)f2bf(bf2f((u16)(hd.y >> 16))   + a3) << 16);
    uint2 o = {o0, o1};
    *(uint2*)(xin + (size_t)n * 128 + g * 4) = o;
}

// =============== fused layer: GEMM1 + LN + ReLU + GEMM2 (+resid) + epilogue ===============
// Weights read as B-fragments straight from global (L2-resident, pre-transposed by k_prep).
// LDS only ~23 KB -> 2 blocks/CU at 512 threads, 4 waves/SIMD.
__global__ __launch_bounds__(512, 4) void k_fused(
    const u16* __restrict__ xin, float* __restrict__ h,
    const u16* __restrict__ tW1, const float* __restrict__ b1,
    const float* __restrict__ g1, const float* __restrict__ bb1,
    const u16* __restrict__ tW2, const float* __restrict__ b2,
    const float* __restrict__ gno, const float* __restrict__ bno,
    u16* __restrict__ h2_out, const int* __restrict__ batch,
    float* __restrict__ pool, float* __restrict__ cnt,
    int resid, int do_pool) {
    __shared__ __align__(16) u16 sY[8][16 * 72];   // per-wave y staging   18432 B
    __shared__ float sP[1152];                     // b1|g1|bb1|b2|gno|bno  4608 B
    int tid = threadIdx.x;
    if (tid < 256) { sP[tid] = b1[tid]; sP[256 + tid] = g1[tid]; sP[512 + tid] = bb1[tid]; }
    if (tid < 128) { sP[768 + tid] = b2[tid]; sP[896 + tid] = gno[tid]; sP[1024 + tid] = bno[tid]; }
    __syncthreads();

    int wave = tid >> 6, lane = tid & 63, q = lane >> 4, c = lane & 15;
    u16* yst = sY[wave];
    for (int tile = blockIdx.x * 8 + wave; tile < N_NODES / 16; tile += gridDim.x * 8) {
        int n0 = tile * 16;
        // ---- A fragments straight from xin (bf16) ----
        const short8* xp = (const short8*)(xin + (size_t)(n0 + c) * 128);
        short8 af[4];
        #pragma unroll
        for (int ks = 0; ks < 4; ks++) af[ks] = xp[ks * 4 + q];
        // ---- GEMM1 (B-frags from global tW1: row n, k contiguous) ----
        f32x4 acc[16];
        #pragma unroll
        for (int t = 0; t < 16; t++) {
            f32x4 a4 = {0.f, 0.f, 0.f, 0.f};
            const short8* bp = (const short8*)(tW1 + (size_t)(t * 16 + c) * 128);
            #pragma unroll
            for (int ks = 0; ks < 4; ks++)
                a4 = __builtin_amdgcn_mfma_f32_16x16x32_bf16(af[ks], bp[ks * 4 + q], a4, 0, 0, 0);
            acc[t] = a4;
        }
        // ---- +b1, LN over 256, ReLU (in-register; rows live in one quad) ----
        float sm[4] = {0, 0, 0, 0}, sq[4] = {0, 0, 0, 0};
        #pragma unroll
        for (int t = 0; t < 16; t++)
            #pragma unroll
            for (int i = 0; i < 4; i++) {
                float v = acc[t][i] + sP[t * 16 + c];
                acc[t][i] = v; sm[i] += v; sq[i] += v * v;
            }
        #pragma unroll
        for (int i = 0; i < 4; i++)
            #pragma unroll
            for (int m = 1; m < 16; m <<= 1) { sm[i] += __shfl_xor(sm[i], m, 64); sq[i] += __shfl_xor(sq[i], m, 64); }
        float mean[4], rs[4];
        #pragma unroll
        for (int i = 0; i < 4; i++) {
            mean[i] = sm[i] * (1.f / 256.f);
            float var = fmaxf(sq[i] * (1.f / 256.f) - mean[i] * mean[i], 0.f);
            rs[i] = rsqrtf(var + EPS_LN);
        }
        #pragma unroll
        for (int t = 0; t < 16; t++)
            #pragma unroll
            for (int i = 0; i < 4; i++) {
                int n = t * 16 + c;
                acc[t][i] = fmaxf(sP[256 + n] * (acc[t][i] - mean[i]) * rs[i] + sP[512 + n], 0.f);
            }
        // ---- GEMM2 via 4 chunks of K=64 (wave-private LDS transpose, no barriers) ----
        f32x4 acc2[8];
        #pragma unroll
        for (int t2 = 0; t2 < 8; t2++) acc2[t2] = (f32x4){0.f, 0.f, 0.f, 0.f};
        #pragma unroll
        for (int ch = 0; ch < 4; ch++) {
            #pragma unroll
            for (int tt = 0; tt < 4; tt++) {
                int t = ch * 4 + tt;
                #pragma unroll
                for (int i = 0; i < 4; i++) yst[(q * 4 + i) * 72 + tt * 16 + c] = f2bf(acc[t][i]);
            }
            #pragma unroll
            for (int ksl = 0; ksl < 2; ksl++) {
                short8 a2 = *(const short8*)(yst + c * 72 + ksl * 32 + q * 8);
                #pragma unroll
                for (int t2 = 0; t2 < 8; t2++) {
                    const short8* bp2 = (const short8*)(tW2 + (size_t)(t2 * 16 + c) * 256 + ch * 64 + ksl * 32);
                    acc2[t2] = __builtin_amdgcn_mfma_f32_16x16x32_bf16(a2, bp2[q], acc2[t2], 0, 0, 0);
                }
            }
        }
        // ---- epilogue: +b2 (+resid), then LN over 128 ----
        float* hb = h + (size_t)n0 * 128;
        float sm2[4] = {0, 0, 0, 0}, sq2[4] = {0, 0, 0, 0};
        float vout[8][4];
        #pragma unroll
        for (int t2 = 0; t2 < 8; t2++)
            #pragma unroll
            for (int i = 0; i < 4; i++) {
                float v = acc2[t2][i] + sP[768 + t2 * 16 + c];
                if (resid) v += hb[(q * 4 + i) * 128 + t2 * 16 + c];
                vout[t2][i] = v; sm2[i] += v; sq2[i] += v * v;
            }
        #pragma unroll
        for (int i = 0; i < 4; i++)
            #pragma unroll
            for (int m = 1; m < 16; m <<= 1) { sm2[i] += __shfl_xor(sm2[i], m, 64); sq2[i] += __shfl_xor(sq2[i], m, 64); }
        float mean2[4], rs2[4];
        #pragma unroll
        for (int i = 0; i < 4; i++) {
            mean2[i] = sm2[i] * (1.f / 128.f);
            float var = fmaxf(sq2[i] * (1.f / 128.f) - mean2[i] * mean2[i], 0.f);
            rs2[i] = rsqrtf(var + EPS_LN);
        }
        if (!do_pool) {
            u16* h2b = h2_out + (size_t)n0 * 128;
            #pragma unroll
            for (int t2 = 0; t2 < 8; t2++)
                #pragma unroll
                for (int i = 0; i < 4; i++) {
                    int col = t2 * 16 + c, idx = (q * 4 + i) * 128 + col;
                    float v = vout[t2][i];
                    hb[idx] = v;                                  // residual for next layer
                    float o = sP[896 + col] * (v - mean2[i]) * rs2[i] + sP[1024 + col];
                    h2b[idx] = f2bf(fmaxf(o, 0.f));               // next conv input
                }
        } else {
            int bg[4];
            #pragma unroll
            for (int i = 0; i < 4; i++) bg[i] = batch[n0 + q * 4 + i];
            #pragma unroll
            for (int t2 = 0; t2 < 8; t2++)
                #pragma unroll
                for (int i = 0; i < 4; i++) {
                    int col = t2 * 16 + c;
                    float o = sP[896 + col] * (vout[t2][i] - mean2[i]) * rs2[i] + sP[1024 + col];
                    unsafeAtomicAdd(&pool[(size_t)bg[i] * 128 + col], o);
                }
            if (c == 0)
                #pragma unroll
                for (int i = 0; i < 4; i++) unsafeAtomicAdd(&cnt[bg[i]], 1.f);
        }
    }
}

// =============== readout: sigmoid(mean_pool @ Wp + bp) ===============
__global__ __launch_bounds__(64) void k_read(const float* __restrict__ pool,
                                             const float* __restrict__ cnt,
                                             const float* __restrict__ Wp,
                                             const float* __restrict__ bp,
                                             float* __restrict__ out) {
    int g = blockIdx.x, lane = threadIdx.x;
    float inv = 1.f / fmaxf(cnt[g], 1.f);
    float d = (pool[(size_t)g * 128 + lane] * Wp[lane] +
               pool[(size_t)g * 128 + 64 + lane] * Wp[64 + lane]) * inv;
    float s = wave_sum(d);
    if (lane == 0) out[g] = 1.f / (1.f + expf(-(s + bp[0])));
}

extern "C" void kernel_launch(void* const* d_in, const int* in_sizes, int n_in,
                              void* d_out, int out_size, void* d_ws, size_t ws_size,
                              hipStream_t stream) {
    const float* x   = (const float*)d_in[0];
    const int*   ei  = (const int*)d_in[1];
    const int*   ea  = (const int*)d_in[2];
    const int*   bat = (const int*)d_in[3];
    const float* We  = (const float*)d_in[4];
    const float* be  = (const float*)d_in[5];
    const float* Et  = (const float*)d_in[6];
    const float* W1  = (const float*)d_in[7];
    const float* b1  = (const float*)d_in[8];
    const float* g1  = (const float*)d_in[9];
    const float* bb1 = (const float*)d_in[10];
    const float* W2  = (const float*)d_in[11];
    const float* b2  = (const float*)d_in[12];
    const float* gn  = (const float*)d_in[13];
    const float* bn  = (const float*)d_in[14];
    const float* Wp  = (const float*)d_in[15];
    const float* bp  = (const float*)d_in[16];
    float* out = (float*)d_out;

    char* w = (char*)d_ws;
    float* h    = (float*)w;  w += (size_t)N_NODES * 128 * 4;
    u16*   h2   = (u16*)w;    w += (size_t)N_NODES * 128 * 2;
    u16*   xin  = (u16*)w;    w += (size_t)N_NODES * 128 * 2;
    float* pool = (float*)w;  w += (size_t)NGRAPH * 128 * 4;
    float* cnt  = (float*)w;  w += (size_t)NGRAPH * 4;
    int*   deg  = (int*)w;    w += (size_t)N_NODES * 4;
    int*   offs = (int*)w;    w += (size_t)N_NODES * 4;
    int*   curs = (int*)w;    w += (size_t)N_NODES * 4;
    int*   bsum = (int*)w;    w += 128 * 4;
    int*   csr  = (int*)w;    w += (size_t)N_EDGES * 4;
    u16*   tW1  = (u16*)w;    w += (size_t)4 * 32768 * 2;
    u16*   tW2  = (u16*)w;    w += (size_t)4 * 32768 * 2;

    const int NB_SCAN = (N_NODES + 1023) / 1024;   // 98

    hipMemsetAsync(pool, 0, ((size_t)NGRAPH * 128 + NGRAPH) * 4, stream);
    hipMemsetAsync(deg, 0, (size_t)N_NODES * 4, stream);
    k_prep<<<512, 256, 0, stream>>>(W1, W2, tW1, tW2);
    // CSR build (edges are static across layers — build once per launch)
    k_hist<<<(N_EDGES + 255) / 256, 256, 0, stream>>>(ei, deg);
    k_scan1<<<NB_SCAN, 256, 0, stream>>>(deg, offs, bsum);
    k_scan2<<<1, 128, 0, stream>>>(bsum, NB_SCAN);
    k_scan3<<<NB_SCAN, 256, 0, stream>>>(offs, bsum, curs);
    k_scatter<<<(N_EDGES + 255) / 256, 256, 0, stream>>>(ei, ea, curs, csr);

    k_enc<<<256, 256, 0, stream>>>(x, We, be, h2);
    for (int l = 0; l < 4; l++) {
        k_agg<<<(N_NODES + 7) / 8, 256, 0, stream>>>(offs, deg, csr, Et, h2, xin);
        k_fused<<<512, 512, 0, stream>>>(xin, h,
                                         tW1 + (size_t)l * 32768, b1 + l * 256,
                                         g1 + l * 256, bb1 + l * 256,
                                         tW2 + (size_t)l * 32768, b2 + l * 128,
                                         gn + l * 128, bn + l * 128,
                                         h2, bat, pool, cnt,
                                         l > 0 ? 1 : 0, l == 3 ? 1 : 0);
    }
    k_read<<<NGRAPH, 64, 0, stream>>>(pool, cnt, Wp, bp, out);
}

// Round 6
// 1500.436 us; speedup vs baseline: 1.7677x; 1.7677x over previous
//
#include <hip/hip_runtime.h>

#define N_NODES 100000
#define N_EDGES 600000
#define NGRAPH 512
#define NOPS_T 8
#define EPS_MSG 1e-7f
#define EPS_LN 1e-5f

typedef unsigned short u16;
typedef unsigned int u32;
typedef __attribute__((ext_vector_type(8))) short short8;   // 8 bf16 (4 VGPRs) MFMA A/B frag
typedef __attribute__((ext_vector_type(4))) float f32x4;    // MFMA C/D frag

__device__ __forceinline__ float bf2f(u16 u) {
    union { float f; u32 i; } v; v.i = ((u32)u) << 16; return v.f;
}
__device__ __forceinline__ u16 f2bf(float f) {
    union { float f; u32 i; } v; v.f = f;
    u32 r = (v.i + 0x7fffu + ((v.i >> 16) & 1u)) >> 16;   // RNE
    return (u16)r;
}
__device__ __forceinline__ float wave_sum(float v) {
    #pragma unroll
    for (int off = 32; off > 0; off >>= 1) v += __shfl_xor(v, off, 64);
    return v;
}

// =============== prep: bf16 transposed weights (n-major, k contiguous) ===============
__global__ __launch_bounds__(256) void k_prep(const float* __restrict__ W1,
                                              const float* __restrict__ W2,
                                              u16* __restrict__ tW1,
                                              u16* __restrict__ tW2) {
    int i = blockIdx.x * 256 + threadIdx.x;   // over 4*32768
    if (i >= 4 * 32768) return;
    int l = i >> 15, r = i & 32767;
    int n1 = r >> 7, k1 = r & 127;
    tW1[i] = f2bf(W1[(l << 15) + k1 * 256 + n1]);
    int n2 = r >> 8, k2 = r & 255;
    tW2[i] = f2bf(W2[(l << 15) + k2 * 128 + n2]);
}

// =============== encoder: h2 = bf16(x @ We + be)  (transposed D, vector stores) =======
__global__ __launch_bounds__(256, 1) void k_enc(const float* __restrict__ x,
                                                const float* __restrict__ We,
                                                const float* __restrict__ be,
                                                u16* __restrict__ h2) {
    __shared__ __align__(16) u16 sWe[128 * 136];   // We^T padded (+8): row n, k contiguous
    __shared__ __align__(16) float sB[128];
    int tid = threadIdx.x;
    for (int i = tid; i < 128 * 128; i += 256) { int k = i >> 7, n = i & 127; sWe[n * 136 + k] = f2bf(We[i]); }
    if (tid < 128) sB[tid] = be[tid];
    __syncthreads();
    int wave = tid >> 6, lane = tid & 63, q = lane >> 4, c = lane & 15, qc4 = q * 4;
    for (int tile = blockIdx.x * 4 + wave; tile < N_NODES / 16; tile += gridDim.x * 4) {
        int n0 = tile * 16;
        const float4* xp = (const float4*)(x + (size_t)(n0 + c) * 128);
        short8 bx[4];
        #pragma unroll
        for (int ks = 0; ks < 4; ks++) {
            float4 v0 = xp[ks * 8 + q * 2], v1 = xp[ks * 8 + q * 2 + 1];
            short8 a;
            a[0] = (short)f2bf(v0.x); a[1] = (short)f2bf(v0.y);
            a[2] = (short)f2bf(v0.z); a[3] = (short)f2bf(v0.w);
            a[4] = (short)f2bf(v1.x); a[5] = (short)f2bf(v1.y);
            a[6] = (short)f2bf(v1.z); a[7] = (short)f2bf(v1.w);
            bx[ks] = a;
        }
        u16* h2b = h2 + (size_t)(n0 + c) * 128;
        #pragma unroll
        for (int t = 0; t < 8; t++) {
            f32x4 a4 = *(const f32x4*)(sB + t * 16 + qc4);      // bias pre-init
            const short8* ap = (const short8*)(sWe + (t * 16 + c) * 136);
            #pragma unroll
            for (int ks = 0; ks < 4; ks++)
                a4 = __builtin_amdgcn_mfma_f32_16x16x32_bf16(ap[ks * 4 + q], bx[ks], a4, 0, 0, 0);
            // D (transposed): lane(q,c) holds chans t*16+q*4..+3 of node n0+c
            uint2 pk;
            pk.x = (u32)f2bf(a4[0]) | ((u32)f2bf(a4[1]) << 16);
            pk.y = (u32)f2bf(a4[2]) | ((u32)f2bf(a4[3]) << 16);
            *(uint2*)(h2b + t * 16 + qc4) = pk;
        }
    }
}

// =============== CSR build (once per launch; edges static across layers) ===============
__global__ __launch_bounds__(256) void k_hist(const int* __restrict__ ei, int* __restrict__ deg) {
    int e = blockIdx.x * 256 + threadIdx.x;
    if (e < N_EDGES) atomicAdd(&deg[ei[N_EDGES + e]], 1);
}

__global__ __launch_bounds__(256) void k_scan1(const int* __restrict__ deg,
                                               int* __restrict__ offs,
                                               int* __restrict__ bsum) {
    __shared__ int swv[4];
    int b = blockIdx.x, t = threadIdx.x;
    int base = b * 1024 + t * 4;
    int4 v = {0, 0, 0, 0};
    if (base < N_NODES) v = *(const int4*)(deg + base);   // N_NODES % 4 == 0
    int s = v.x + v.y + v.z + v.w;
    int lane = t & 63, wid = t >> 6;
    int incl = s;
    #pragma unroll
    for (int off = 1; off < 64; off <<= 1) {
        int o = __shfl_up(incl, off, 64);
        if (lane >= off) incl += o;
    }
    if (lane == 63) swv[wid] = incl;
    __syncthreads();
    int wbase = 0;
    #pragma unroll
    for (int w = 0; w < 4; w++) if (w < wid) wbase += swv[w];
    int ex = wbase + incl - s;
    if (base < N_NODES) {
        offs[base]     = ex;
        offs[base + 1] = ex + v.x;
        offs[base + 2] = ex + v.x + v.y;
        offs[base + 3] = ex + v.x + v.y + v.z;
    }
    if (t == 255) bsum[b] = wbase + incl;
}

__global__ __launch_bounds__(128) void k_scan2(int* __restrict__ bsum, int nb) {
    __shared__ int s[128];
    int t = threadIdx.x;
    int v = t < nb ? bsum[t] : 0;
    s[t] = v;
    __syncthreads();
    for (int off = 1; off < 128; off <<= 1) {
        int a = t >= off ? s[t - off] : 0;
        __syncthreads();
        s[t] += a;
        __syncthreads();
    }
    if (t < nb) bsum[t] = s[t] - v;
}

__global__ __launch_bounds__(256) void k_scan3(int* __restrict__ offs,
                                               const int* __restrict__ bsum,
                                               int* __restrict__ cursor) {
    int b = blockIdx.x, t = threadIdx.x;
    int base = b * 1024 + t * 4;
    if (base >= N_NODES) return;
    int add = bsum[b];
    #pragma unroll
    for (int i = 0; i < 4; i++) {
        int o = offs[base + i] + add;
        offs[base + i] = o;
        cursor[base + i] = o;
    }
}

__global__ __launch_bounds__(256) void k_scatter(const int* __restrict__ ei,
                                                 const int* __restrict__ ea,
                                                 int* __restrict__ cursor,
                                                 int* __restrict__ csr) {
    int e = blockIdx.x * 256 + threadIdx.x;
    if (e >= N_EDGES) return;
    int s = ei[e], d = ei[N_EDGES + e], a = ea[e];
    int pos = atomicAdd(&cursor[d], 1);
    csr[pos] = s | (a << 24);                 // src < 2^17, attr < 8
}

// =============== aggregate (gather, no atomics): xin = bf16(h2 + sum msgs) ===============
__global__ __launch_bounds__(256) void k_agg(const int* __restrict__ offs,
                                             const int* __restrict__ deg,
                                             const int* __restrict__ csr,
                                             const float* __restrict__ Et,
                                             const u16* __restrict__ h2,
                                             u16* __restrict__ xin) {
    __shared__ float4 sE[NOPS_T * 32];
    int tid = threadIdx.x;
    sE[tid] = ((const float4*)Et)[tid];
    __syncthreads();
    int n = blockIdx.x * 8 + (tid >> 5);
    if (n >= N_NODES) return;
    int g = tid & 31;
    float a0 = 0.f, a1 = 0.f, a2 = 0.f, a3 = 0.f;
    int st = offs[n], dg = deg[n];
    for (int j = 0; j < dg; j++) {
        int p = csr[st + j];
        int s = p & 0xFFFFFF;
        int a = ((u32)p) >> 24;
        uint2 hv = *(const uint2*)(h2 + (size_t)s * 128 + g * 4);
        float4 ev = sE[a * 32 + g];
        a0 += fmaxf(bf2f((u16)(hv.x & 0xffff)) + ev.x, 0.f) + EPS_MSG;
        a1 += fmaxf(bf2f((u16)(hv.x >> 16))    + ev.y, 0.f) + EPS_MSG;
        a2 += fmaxf(bf2f((u16)(hv.y & 0xffff)) + ev.z, 0.f) + EPS_MSG;
        a3 += fmaxf(bf2f((u16)(hv.y >> 16))    + ev.w, 0.f) + EPS_MSG;
    }
    uint2 hd = *(const uint2*)(h2 + (size_t)n * 128 + g * 4);
    u32 o0 = (u32)f2bf(bf2f((u16)(hd.x & 0xffff)) + a0) |
             ((u32)f2bf(bf2f((u16)(hd.x >> 16))   + a1) << 16);
    u32 o1 = (u32)f2bf(bf2f((u16)(hd.y & 0xffff)) + a2) |
             ((u32)f2bf(bf2f((u16)(hd.y >> 16))   + a3) << 16);
    uint2 o = {o0, o1};
    *(uint2*)(xin + (size_t)n * 128 + g * 4) = o;
}

// =============== fused layer: transposed MFMA pipeline ===============
// D transposed via operand swap: lane(q,c) holds chans [t*16+q*4 .. +3] of node n0+c.
// All global I/O vectorized (>=8B/lane); bias folded into MFMA C-init; weights in LDS.
// LDS: 69632 + 67584 + 20480 + 4608 = 162304 B -> 1 block/CU, 512 thr (2 waves/SIMD).
__global__ __launch_bounds__(512, 2) void k_fused(
    const u16* __restrict__ xin, float* __restrict__ h,
    const u16* __restrict__ tW1, const float* __restrict__ b1,
    const float* __restrict__ g1, const float* __restrict__ bb1,
    const u16* __restrict__ tW2, const float* __restrict__ b2,
    const float* __restrict__ gno, const float* __restrict__ bno,
    u16* __restrict__ h2_out, const int* __restrict__ batch,
    float* __restrict__ pool, float* __restrict__ cnt,
    int resid, int do_pool) {
    __shared__ __align__(16) u16 sW1[256 * 136];   // W1^T: [n][k], +8 pad
    __shared__ __align__(16) u16 sW2[128 * 264];   // W2^T: [n][k], +8 pad
    __shared__ __align__(16) u16 sYT[8][16 * 80];  // per-wave y staging: [node 16][chan-local 64 +16 pad]
    __shared__ __align__(16) float sP[1152];       // b1|g1|bb1 (256) b2|gno|bno (128)
    int tid = threadIdx.x;
    for (int i = tid; i < 4096; i += 512) {                  // stage W1^T (16B chunks)
        int n = i >> 4, k8 = (i & 15) << 3;
        *(short8*)(sW1 + n * 136 + k8) = *(const short8*)(tW1 + n * 128 + k8);
    }
    for (int i = tid; i < 4096; i += 512) {                  // stage W2^T
        int n = i >> 5, k8 = (i & 31) << 3;
        *(short8*)(sW2 + n * 264 + k8) = *(const short8*)(tW2 + n * 256 + k8);
    }
    if (tid < 256) { sP[tid] = b1[tid]; sP[256 + tid] = g1[tid]; sP[512 + tid] = bb1[tid]; }
    if (tid < 128) { sP[768 + tid] = b2[tid]; sP[896 + tid] = gno[tid]; sP[1024 + tid] = bno[tid]; }
    __syncthreads();

    int wave = tid >> 6, lane = tid & 63, q = lane >> 4, c = lane & 15, qc4 = q * 4;
    u16* yst = sYT[wave];
    for (int tile = blockIdx.x * 8 + wave; tile < N_NODES / 16; tile += gridDim.x * 8) {
        int n0 = tile * 16;
        // ---- B fragments (x rows, k-contiguous) ----
        const short8* xp = (const short8*)(xin + (size_t)(n0 + c) * 128);
        short8 bx[4];
        #pragma unroll
        for (int ks = 0; ks < 4; ks++) bx[ks] = xp[ks * 4 + q];
        // ---- GEMM1: yT = W1^T x ; bias pre-init in C ----
        f32x4 acc[16];
        #pragma unroll
        for (int t = 0; t < 16; t++) {
            f32x4 a4 = *(const f32x4*)(sP + t * 16 + qc4);
            const short8* ap = (const short8*)(sW1 + (t * 16 + c) * 136);
            #pragma unroll
            for (int ks = 0; ks < 4; ks++)
                a4 = __builtin_amdgcn_mfma_f32_16x16x32_bf16(ap[ks * 4 + q], bx[ks], a4, 0, 0, 0);
            acc[t] = a4;
        }
        // ---- LN over 256 (channels live on the 4 q-lanes of column c) ----
        float sm = 0.f, sq = 0.f;
        #pragma unroll
        for (int t = 0; t < 16; t++)
            #pragma unroll
            for (int i = 0; i < 4; i++) { float v = acc[t][i]; sm += v; sq += v * v; }
        sm += __shfl_xor(sm, 16, 64); sm += __shfl_xor(sm, 32, 64);
        sq += __shfl_xor(sq, 16, 64); sq += __shfl_xor(sq, 32, 64);
        float mean = sm * (1.f / 256.f);
        float var = fmaxf(sq * (1.f / 256.f) - mean * mean, 0.f);
        float rs = rsqrtf(var + EPS_LN);
        // ---- residual prefetch (vector, hidden under GEMM2) ----
        f32x4 rr[8];
        const float* hbr = h + (size_t)(n0 + c) * 128;
        if (resid) {
            #pragma unroll
            for (int t2 = 0; t2 < 8; t2++) rr[t2] = *(const f32x4*)(hbr + t2 * 16 + qc4);
        }
        // ---- GEMM2 in 4 chunks of 64 chans (wave-private LDS transpose) ----
        f32x4 acc2[8];
        #pragma unroll
        for (int t2 = 0; t2 < 8; t2++) acc2[t2] = *(const f32x4*)(sP + 768 + t2 * 16 + qc4);
        #pragma unroll
        for (int ch = 0; ch < 4; ch++) {
            #pragma unroll
            for (int tt = 0; tt < 4; tt++) {
                int t = ch * 4 + tt;
                f32x4 gg = *(const f32x4*)(sP + 256 + t * 16 + qc4);
                f32x4 bb = *(const f32x4*)(sP + 512 + t * 16 + qc4);
                float v0 = fmaxf(gg[0] * (acc[t][0] - mean) * rs + bb[0], 0.f);
                float v1 = fmaxf(gg[1] * (acc[t][1] - mean) * rs + bb[1], 0.f);
                float v2 = fmaxf(gg[2] * (acc[t][2] - mean) * rs + bb[2], 0.f);
                float v3 = fmaxf(gg[3] * (acc[t][3] - mean) * rs + bb[3], 0.f);
                uint2 pk;
                pk.x = (u32)f2bf(v0) | ((u32)f2bf(v1) << 16);
                pk.y = (u32)f2bf(v2) | ((u32)f2bf(v3) << 16);
                *(uint2*)(yst + c * 80 + tt * 16 + qc4) = pk;    // y[node c][chan-local]
            }
            #pragma unroll
            for (int ksl = 0; ksl < 2; ksl++) {
                short8 by = *(const short8*)(yst + c * 80 + ksl * 32 + q * 8);
                int ks2 = ch * 2 + ksl;
                #pragma unroll
                for (int t2 = 0; t2 < 8; t2++) {
                    const short8* ap2 = (const short8*)(sW2 + (t2 * 16 + c) * 264);
                    acc2[t2] = __builtin_amdgcn_mfma_f32_16x16x32_bf16(ap2[ks2 * 4 + q], by, acc2[t2], 0, 0, 0);
                }
            }
        }
        // ---- epilogue: (+resid), LN over 128 ----
        float sm2 = 0.f, sq2 = 0.f;
        #pragma unroll
        for (int t2 = 0; t2 < 8; t2++)
            #pragma unroll
            for (int i = 0; i < 4; i++) {
                float v = acc2[t2][i];
                if (resid) v += rr[t2][i];
                acc2[t2][i] = v; sm2 += v; sq2 += v * v;
            }
        sm2 += __shfl_xor(sm2, 16, 64); sm2 += __shfl_xor(sm2, 32, 64);
        sq2 += __shfl_xor(sq2, 16, 64); sq2 += __shfl_xor(sq2, 32, 64);
        float mean2 = sm2 * (1.f / 128.f);
        float var2 = fmaxf(sq2 * (1.f / 128.f) - mean2 * mean2, 0.f);
        float rs2 = rsqrtf(var2 + EPS_LN);
        if (!do_pool) {
            float* hb = h + (size_t)(n0 + c) * 128;
            u16* h2b = h2_out + (size_t)(n0 + c) * 128;
            #pragma unroll
            for (int t2 = 0; t2 < 8; t2++) {
                *(f32x4*)(hb + t2 * 16 + qc4) = acc2[t2];        // residual for next layer
                f32x4 gg = *(const f32x4*)(sP + 896 + t2 * 16 + qc4);
                f32x4 bb = *(const f32x4*)(sP + 1024 + t2 * 16 + qc4);
                float o0 = fmaxf(gg[0] * (acc2[t2][0] - mean2) * rs2 + bb[0], 0.f);
                float o1 = fmaxf(gg[1] * (acc2[t2][1] - mean2) * rs2 + bb[1], 0.f);
                float o2 = fmaxf(gg[2] * (acc2[t2][2] - mean2) * rs2 + bb[2], 0.f);
                float o3 = fmaxf(gg[3] * (acc2[t2][3] - mean2) * rs2 + bb[3], 0.f);
                uint2 pk;
                pk.x = (u32)f2bf(o0) | ((u32)f2bf(o1) << 16);
                pk.y = (u32)f2bf(o2) | ((u32)f2bf(o3) << 16);
                *(uint2*)(h2b + t2 * 16 + qc4) = pk;             // next conv input
            }
        } else {
            int bg = batch[n0 + c];
            float* pb = pool + (size_t)bg * 128;
            #pragma unroll
            for (int t2 = 0; t2 < 8; t2++) {
                f32x4 gg = *(const f32x4*)(sP + 896 + t2 * 16 + qc4);
                f32x4 bb = *(const f32x4*)(sP + 1024 + t2 * 16 + qc4);
                #pragma unroll
                for (int i = 0; i < 4; i++) {
                    float o = gg[i] * (acc2[t2][i] - mean2) * rs2 + bb[i];   // final LN, no relu
                    unsafeAtomicAdd(pb + t2 * 16 + qc4 + i, o);
                }
            }
            if (lane < 16) unsafeAtomicAdd(&cnt[batch[n0 + lane]], 1.f);
        }
    }
}

// =============== readout: sigmoid(mean_pool @ Wp + bp) ===============
__global__ __launch_bounds__(64) void k_read(const float* __restrict__ pool,
                                             const float* __restrict__ cnt,
                                             const float* __restrict__ Wp,
                                             const float* __restrict__ bp,
                                             float* __restrict__ out) {
    int g = blockIdx.x, lane = threadIdx.x;
    float inv = 1.f / fmaxf(cnt[g], 1.f);
    float d = (pool[(size_t)g * 128 + lane] * Wp[lane] +
               pool[(size_t)g * 128 + 64 + lane] * Wp[64 + lane]) * inv;
    float s = wave_sum(d);
    if (lane == 0) out[g] = 1.f / (1.f + expf(-(s + bp[0])));
}

extern "C" void kernel_launch(void* const* d_in, const int* in_sizes, int n_in,
                              void* d_out, int out_size, void* d_ws, size_t ws_size,
                              hipStream_t stream) {
    const float* x   = (const float*)d_in[0];
    const int*   ei  = (const int*)d_in[1];
    const int*   ea  = (const int*)d_in[2];
    const int*   bat = (const int*)d_in[3];
    const float* We  = (const float*)d_in[4];
    const float* be  = (const float*)d_in[5];
    const float* Et  = (const float*)d_in[6];
    const float* W1  = (const float*)d_in[7];
    const float* b1  = (const float*)d_in[8];
    const float* g1  = (const float*)d_in[9];
    const float* bb1 = (const float*)d_in[10];
    const float* W2  = (const float*)d_in[11];
    const float* b2  = (const float*)d_in[12];
    const float* gn  = (const float*)d_in[13];
    const float* bn  = (const float*)d_in[14];
    const float* Wp  = (const float*)d_in[15];
    const float* bp  = (const float*)d_in[16];
    float* out = (float*)d_out;

    char* w = (char*)d_ws;
    float* h    = (float*)w;  w += (size_t)N_NODES * 128 * 4;
    u16*   h2   = (u16*)w;    w += (size_t)N_NODES * 128 * 2;
    u16*   xin  = (u16*)w;    w += (size_t)N_NODES * 128 * 2;
    float* pool = (float*)w;  w += (size_t)NGRAPH * 128 * 4;
    float* cnt  = (float*)w;  w += (size_t)NGRAPH * 4;
    int*   deg  = (int*)w;    w += (size_t)N_NODES * 4;
    int*   offs = (int*)w;    w += (size_t)N_NODES * 4;
    int*   curs = (int*)w;    w += (size_t)N_NODES * 4;
    int*   bsum = (int*)w;    w += 128 * 4;
    int*   csr  = (int*)w;    w += (size_t)N_EDGES * 4;
    u16*   tW1  = (u16*)w;    w += (size_t)4 * 32768 * 2;
    u16*   tW2  = (u16*)w;    w += (size_t)4 * 32768 * 2;

    const int NB_SCAN = (N_NODES + 1023) / 1024;   // 98

    hipMemsetAsync(pool, 0, ((size_t)NGRAPH * 128 + NGRAPH) * 4, stream);
    hipMemsetAsync(deg, 0, (size_t)N_NODES * 4, stream);
    k_prep<<<512, 256, 0, stream>>>(W1, W2, tW1, tW2);
    // CSR build (edges are static across layers — build once per launch)
    k_hist<<<(N_EDGES + 255) / 256, 256, 0, stream>>>(ei, deg);
    k_scan1<<<NB_SCAN, 256, 0, stream>>>(deg, offs, bsum);
    k_scan2<<<1, 128, 0, stream>>>(bsum, NB_SCAN);
    k_scan3<<<NB_SCAN, 256, 0, stream>>>(offs, bsum, curs);
    k_scatter<<<(N_EDGES + 255) / 256, 256, 0, stream>>>(ei, ea, curs, csr);

    k_enc<<<256, 256, 0, stream>>>(x, We, be, h2);
    for (int l = 0; l < 4; l++) {
        k_agg<<<(N_NODES + 7) / 8, 256, 0, stream>>>(offs, deg, csr, Et, h2, xin);
        k_fused<<<256, 512, 0, stream>>>(xin, h,
                                         tW1 + (size_t)l * 32768, b1 + l * 256,
                                         g1 + l * 256, bb1 + l * 256,
                                         tW2 + (size_t)l * 32768, b2 + l * 128,
                                         gn + l * 128, bn + l * 128,
                                         h2, bat, pool, cnt,
                                         l > 0 ? 1 : 0, l == 3 ? 1 : 0);
    }
    k_read<<<NGRAPH, 64, 0, stream>>>(pool, cnt, Wp, bp, out);
}

// Round 7
// 880.593 us; speedup vs baseline: 3.0120x; 1.7039x over previous
//
#include <hip/hip_runtime.h>

#define N_NODES 100000
#define N_EDGES 600000
#define NGRAPH 512
#define NOPS_T 8
#define EPS_MSG 1e-7f
#define EPS_LN 1e-5f

typedef unsigned short u16;
typedef unsigned int u32;
typedef __attribute__((ext_vector_type(8))) short short8;   // 8 bf16 (4 VGPRs) MFMA A/B frag
typedef __attribute__((ext_vector_type(4))) float f32x4;    // MFMA C/D frag

__device__ __forceinline__ float bf2f(u16 u) {
    union { float f; u32 i; } v; v.i = ((u32)u) << 16; return v.f;
}
__device__ __forceinline__ u16 f2bf(float f) {
    union { float f; u32 i; } v; v.f = f;
    u32 r = (v.i + 0x7fffu + ((v.i >> 16) & 1u)) >> 16;   // RNE
    return (u16)r;
}
__device__ __forceinline__ float wave_sum(float v) {
    #pragma unroll
    for (int off = 32; off > 0; off >>= 1) v += __shfl_xor(v, off, 64);
    return v;
}

// =============== prep: bf16 transposed weights (n-major, k contiguous) ===============
__global__ __launch_bounds__(256) void k_prep(const float* __restrict__ W1,
                                              const float* __restrict__ W2,
                                              u16* __restrict__ tW1,
                                              u16* __restrict__ tW2) {
    int i = blockIdx.x * 256 + threadIdx.x;   // over 4*32768
    if (i >= 4 * 32768) return;
    int l = i >> 15, r = i & 32767;
    int n1 = r >> 7, k1 = r & 127;
    tW1[i] = f2bf(W1[(l << 15) + k1 * 256 + n1]);
    int n2 = r >> 8, k2 = r & 255;
    tW2[i] = f2bf(W2[(l << 15) + k2 * 128 + n2]);
}

// =============== encoder: h2 = bf16(x @ We + be)  (r4-proven layout) ===============
__global__ __launch_bounds__(256, 1) void k_enc(const float* __restrict__ x,
                                                const float* __restrict__ We,
                                                const float* __restrict__ be,
                                                u16* __restrict__ h2) {
    __shared__ __align__(16) u16 sWe[128 * 136];   // We^T padded (+8): row n, k contiguous
    __shared__ float sB[128];
    int tid = threadIdx.x;
    for (int i = tid; i < 128 * 128; i += 256) { int k = i >> 7, n = i & 127; sWe[n * 136 + k] = f2bf(We[i]); }
    if (tid < 128) sB[tid] = be[tid];
    __syncthreads();
    int wave = tid >> 6, lane = tid & 63, q = lane >> 4, c = lane & 15;
    for (int tile = blockIdx.x * 4 + wave; tile < N_NODES / 16; tile += gridDim.x * 4) {
        int n0 = tile * 16;
        const float4* xp = (const float4*)(x + (size_t)(n0 + c) * 128);
        short8 af[4];
        #pragma unroll
        for (int ks = 0; ks < 4; ks++) {
            float4 v0 = xp[ks * 8 + q * 2], v1 = xp[ks * 8 + q * 2 + 1];
            short8 a;
            a[0] = (short)f2bf(v0.x); a[1] = (short)f2bf(v0.y);
            a[2] = (short)f2bf(v0.z); a[3] = (short)f2bf(v0.w);
            a[4] = (short)f2bf(v1.x); a[5] = (short)f2bf(v1.y);
            a[6] = (short)f2bf(v1.z); a[7] = (short)f2bf(v1.w);
            af[ks] = a;
        }
        f32x4 acc[8];
        #pragma unroll
        for (int t = 0; t < 8; t++) {
            f32x4 a4 = {0.f, 0.f, 0.f, 0.f};
            const short8* bp = (const short8*)(sWe + (t * 16 + c) * 136);
            #pragma unroll
            for (int ks = 0; ks < 4; ks++)
                a4 = __builtin_amdgcn_mfma_f32_16x16x32_bf16(af[ks], bp[ks * 4 + q], a4, 0, 0, 0);
            acc[t] = a4;
        }
        u16* h2b = h2 + (size_t)n0 * 128;
        #pragma unroll
        for (int t = 0; t < 8; t++)
            #pragma unroll
            for (int i = 0; i < 4; i++) {
                int idx = (q * 4 + i) * 128 + t * 16 + c;     // D: row=q*4+i (node), col=t*16+c (chan)
                h2b[idx] = f2bf(acc[t][i] + sB[t * 16 + c]);
            }
    }
}

// =============== CSR build (once per launch; edges static across layers) ===============
__global__ __launch_bounds__(256) void k_hist(const int* __restrict__ ei, int* __restrict__ deg) {
    int e = blockIdx.x * 256 + threadIdx.x;
    if (e < N_EDGES) atomicAdd(&deg[ei[N_EDGES + e]], 1);
}

__global__ __launch_bounds__(256) void k_scan1(const int* __restrict__ deg,
                                               int* __restrict__ offs,
                                               int* __restrict__ bsum) {
    __shared__ int swv[4];
    int b = blockIdx.x, t = threadIdx.x;
    int base = b * 1024 + t * 4;
    int4 v = {0, 0, 0, 0};
    if (base < N_NODES) v = *(const int4*)(deg + base);   // N_NODES % 4 == 0
    int s = v.x + v.y + v.z + v.w;
    int lane = t & 63, wid = t >> 6;
    int incl = s;
    #pragma unroll
    for (int off = 1; off < 64; off <<= 1) {
        int o = __shfl_up(incl, off, 64);
        if (lane >= off) incl += o;
    }
    if (lane == 63) swv[wid] = incl;
    __syncthreads();
    int wbase = 0;
    #pragma unroll
    for (int w = 0; w < 4; w++) if (w < wid) wbase += swv[w];
    int ex = wbase + incl - s;
    if (base < N_NODES) {
        offs[base]     = ex;
        offs[base + 1] = ex + v.x;
        offs[base + 2] = ex + v.x + v.y;
        offs[base + 3] = ex + v.x + v.y + v.z;
    }
    if (t == 255) bsum[b] = wbase + incl;
}

__global__ __launch_bounds__(128) void k_scan2(int* __restrict__ bsum, int nb) {
    __shared__ int s[128];
    int t = threadIdx.x;
    int v = t < nb ? bsum[t] : 0;
    s[t] = v;
    __syncthreads();
    for (int off = 1; off < 128; off <<= 1) {
        int a = t >= off ? s[t - off] : 0;
        __syncthreads();
        s[t] += a;
        __syncthreads();
    }
    if (t < nb) bsum[t] = s[t] - v;
}

__global__ __launch_bounds__(256) void k_scan3(int* __restrict__ offs,
                                               const int* __restrict__ bsum,
                                               int* __restrict__ cursor) {
    int b = blockIdx.x, t = threadIdx.x;
    int base = b * 1024 + t * 4;
    if (base >= N_NODES) return;
    int add = bsum[b];
    #pragma unroll
    for (int i = 0; i < 4; i++) {
        int o = offs[base + i] + add;
        offs[base + i] = o;
        cursor[base + i] = o;
    }
}

__global__ __launch_bounds__(256) void k_scatter(const int* __restrict__ ei,
                                                 const int* __restrict__ ea,
                                                 int* __restrict__ cursor,
                                                 int* __restrict__ csr) {
    int e = blockIdx.x * 256 + threadIdx.x;
    if (e >= N_EDGES) return;
    int s = ei[e], d = ei[N_EDGES + e], a = ea[e];
    int pos = atomicAdd(&cursor[d], 1);
    csr[pos] = s | (a << 24);                 // src < 2^17, attr < 8
}

// =============== aggregate (gather, no atomics): xin = bf16(h2 + sum msgs) ===============
__global__ __launch_bounds__(256) void k_agg(const int* __restrict__ offs,
                                             const int* __restrict__ deg,
                                             const int* __restrict__ csr,
                                             const float* __restrict__ Et,
                                             const u16* __restrict__ h2,
                                             u16* __restrict__ xin) {
    __shared__ float4 sE[NOPS_T * 32];
    int tid = threadIdx.x;
    sE[tid] = ((const float4*)Et)[tid];
    __syncthreads();
    int n = blockIdx.x * 8 + (tid >> 5);
    if (n >= N_NODES) return;
    int g = tid & 31;
    float a0 = 0.f, a1 = 0.f, a2 = 0.f, a3 = 0.f;
    int st = offs[n], dg = deg[n];
    int j = 0;
    for (; j + 2 <= dg; j += 2) {               // 2 edges in flight
        int p0 = csr[st + j], p1 = csr[st + j + 1];
        int s0 = p0 & 0xFFFFFF, at0 = ((u32)p0) >> 24;
        int s1 = p1 & 0xFFFFFF, at1 = ((u32)p1) >> 24;
        uint2 h0 = *(const uint2*)(h2 + (size_t)s0 * 128 + g * 4);
        uint2 h1 = *(const uint2*)(h2 + (size_t)s1 * 128 + g * 4);
        float4 e0 = sE[at0 * 32 + g], e1 = sE[at1 * 32 + g];
        a0 += fmaxf(bf2f((u16)(h0.x & 0xffff)) + e0.x, 0.f) + EPS_MSG;
        a1 += fmaxf(bf2f((u16)(h0.x >> 16))    + e0.y, 0.f) + EPS_MSG;
        a2 += fmaxf(bf2f((u16)(h0.y & 0xffff)) + e0.z, 0.f) + EPS_MSG;
        a3 += fmaxf(bf2f((u16)(h0.y >> 16))    + e0.w, 0.f) + EPS_MSG;
        a0 += fmaxf(bf2f((u16)(h1.x & 0xffff)) + e1.x, 0.f) + EPS_MSG;
        a1 += fmaxf(bf2f((u16)(h1.x >> 16))    + e1.y, 0.f) + EPS_MSG;
        a2 += fmaxf(bf2f((u16)(h1.y & 0xffff)) + e1.z, 0.f) + EPS_MSG;
        a3 += fmaxf(bf2f((u16)(h1.y >> 16))    + e1.w, 0.f) + EPS_MSG;
    }
    if (j < dg) {
        int p = csr[st + j];
        int s = p & 0xFFFFFF;
        int a = ((u32)p) >> 24;
        uint2 hv = *(const uint2*)(h2 + (size_t)s * 128 + g * 4);
        float4 ev = sE[a * 32 + g];
        a0 += fmaxf(bf2f((u16)(hv.x & 0xffff)) + ev.x, 0.f) + EPS_MSG;
        a1 += fmaxf(bf2f((u16)(hv.x >> 16))    + ev.y, 0.f) + EPS_MSG;
        a2 += fmaxf(bf2f((u16)(hv.y & 0xffff)) + ev.z, 0.f) + EPS_MSG;
        a3 += fmaxf(bf2f((u16)(hv.y >> 16))    + ev.w, 0.f) + EPS_MSG;
    }
    uint2 hd = *(const uint2*)(h2 + (size_t)n * 128 + g * 4);
    u32 o0 = (u32)f2bf(bf2f((u16)(hd.x & 0xffff)) + a0) |
             ((u32)f2bf(bf2f((u16)(hd.x >> 16))   + a1) << 16);
    u32 o1 = (u32)f2bf(bf2f((u16)(hd.y & 0xffff)) + a2) |
             ((u32)f2bf(bf2f((u16)(hd.y >> 16))   + a3) << 16);
    uint2 o = {o0, o1};
    *(uint2*)(xin + (size_t)n * 128 + g * 4) = o;
}

// =============== fused layer: r4 core, 1024 threads (16 waves = 4/SIMD) ===============
// LDS: sW1 69632 + sW2 67584 + sY 20480 + sP 4608 = 162304 B -> 1 block/CU.
// GEMM2 transpose chunked at 32 chans so 16 wave-private staging buffers fit.
__global__ __launch_bounds__(1024, 4) void k_fused(
    const u16* __restrict__ xin, float* __restrict__ h,
    const u16* __restrict__ tW1, const float* __restrict__ b1,
    const float* __restrict__ g1, const float* __restrict__ bb1,
    const u16* __restrict__ tW2, const float* __restrict__ b2,
    const float* __restrict__ gno, const float* __restrict__ bno,
    u16* __restrict__ h2_out, const int* __restrict__ batch,
    float* __restrict__ pool, float* __restrict__ cnt,
    int resid, int do_pool) {
    __shared__ __align__(16) u16 sW1[256 * 136];   // W1^T: [n][k], +8 pad
    __shared__ __align__(16) u16 sW2[128 * 264];   // W2^T: [n][k], +8 pad
    __shared__ __align__(16) u16 sY[16][16 * 40];  // per-wave y staging: 16 nodes x (32+8) chans
    __shared__ float sP[1152];                     // b1|g1|bb1 (256) b2|gno|bno (128)
    int tid = threadIdx.x;
    for (int i = tid; i < 4096; i += 1024) {                 // stage W1^T (16B chunks)
        int n = i >> 4, k8 = (i & 15) << 3;
        *(short8*)(sW1 + n * 136 + k8) = *(const short8*)(tW1 + n * 128 + k8);
    }
    for (int i = tid; i < 4096; i += 1024) {                 // stage W2^T
        int n = i >> 5, k8 = (i & 31) << 3;
        *(short8*)(sW2 + n * 264 + k8) = *(const short8*)(tW2 + n * 256 + k8);
    }
    if (tid < 256) { sP[tid] = b1[tid]; sP[256 + tid] = g1[tid]; sP[512 + tid] = bb1[tid]; }
    if (tid < 128) { sP[768 + tid] = b2[tid]; sP[896 + tid] = gno[tid]; sP[1024 + tid] = bno[tid]; }
    __syncthreads();

    int wave = tid >> 6, lane = tid & 63, q = lane >> 4, c = lane & 15;
    u16* yst = sY[wave];
    for (int tile = blockIdx.x * 16 + wave; tile < N_NODES / 16; tile += gridDim.x * 16) {
        int n0 = tile * 16;
        // ---- A fragments straight from xin (bf16) ----
        const short8* xp = (const short8*)(xin + (size_t)(n0 + c) * 128);
        short8 af[4];
        #pragma unroll
        for (int ks = 0; ks < 4; ks++) af[ks] = xp[ks * 4 + q];
        // ---- GEMM1 (B-frags from LDS W1^T) ----
        f32x4 acc[16];
        #pragma unroll
        for (int t = 0; t < 16; t++) {
            f32x4 a4 = {0.f, 0.f, 0.f, 0.f};
            const short8* bp = (const short8*)(sW1 + (t * 16 + c) * 136);
            #pragma unroll
            for (int ks = 0; ks < 4; ks++)
                a4 = __builtin_amdgcn_mfma_f32_16x16x32_bf16(af[ks], bp[ks * 4 + q], a4, 0, 0, 0);
            acc[t] = a4;
        }
        // ---- +b1, LN over 256, ReLU (rows live in one quad) ----
        float sm[4] = {0, 0, 0, 0}, sq[4] = {0, 0, 0, 0};
        #pragma unroll
        for (int t = 0; t < 16; t++)
            #pragma unroll
            for (int i = 0; i < 4; i++) {
                float v = acc[t][i] + sP[t * 16 + c];
                acc[t][i] = v; sm[i] += v; sq[i] += v * v;
            }
        #pragma unroll
        for (int i = 0; i < 4; i++)
            #pragma unroll
            for (int m = 1; m < 16; m <<= 1) { sm[i] += __shfl_xor(sm[i], m, 64); sq[i] += __shfl_xor(sq[i], m, 64); }
        float mean[4], rs[4];
        #pragma unroll
        for (int i = 0; i < 4; i++) {
            mean[i] = sm[i] * (1.f / 256.f);
            float var = fmaxf(sq[i] * (1.f / 256.f) - mean[i] * mean[i], 0.f);
            rs[i] = rsqrtf(var + EPS_LN);
        }
        #pragma unroll
        for (int t = 0; t < 16; t++)
            #pragma unroll
            for (int i = 0; i < 4; i++) {
                int n = t * 16 + c;
                acc[t][i] = fmaxf(sP[256 + n] * (acc[t][i] - mean[i]) * rs[i] + sP[512 + n], 0.f);
            }
        // ---- residual prefetch (between GEMMs; D-layout addresses, quad-coalesced) ----
        float rr[8][4];
        float* hb = h + (size_t)n0 * 128;
        if (resid) {
            #pragma unroll
            for (int t2 = 0; t2 < 8; t2++)
                #pragma unroll
                for (int i = 0; i < 4; i++) rr[t2][i] = hb[(q * 4 + i) * 128 + t2 * 16 + c];
        }
        // ---- GEMM2 via 8 chunks of K=32 (wave-private LDS transpose, no barriers) ----
        f32x4 acc2[8];
        #pragma unroll
        for (int t2 = 0; t2 < 8; t2++) acc2[t2] = (f32x4){0.f, 0.f, 0.f, 0.f};
        #pragma unroll
        for (int ks2 = 0; ks2 < 8; ks2++) {
            #pragma unroll
            for (int tt = 0; tt < 2; tt++) {
                int t = ks2 * 2 + tt;
                #pragma unroll
                for (int i = 0; i < 4; i++) yst[(q * 4 + i) * 40 + tt * 16 + c] = f2bf(acc[t][i]);
            }
            short8 a2 = *(const short8*)(yst + c * 40 + q * 8);
            #pragma unroll
            for (int t2 = 0; t2 < 8; t2++) {
                const short8* bp2 = (const short8*)(sW2 + (t2 * 16 + c) * 264 + ks2 * 32);
                acc2[t2] = __builtin_amdgcn_mfma_f32_16x16x32_bf16(a2, bp2[q], acc2[t2], 0, 0, 0);
            }
        }
        // ---- epilogue: +b2 (+resid), then LN over 128 ----
        float sm2[4] = {0, 0, 0, 0}, sq2[4] = {0, 0, 0, 0};
        float vout[8][4];
        #pragma unroll
        for (int t2 = 0; t2 < 8; t2++)
            #pragma unroll
            for (int i = 0; i < 4; i++) {
                float v = acc2[t2][i] + sP[768 + t2 * 16 + c];
                if (resid) v += rr[t2][i];
                vout[t2][i] = v; sm2[i] += v; sq2[i] += v * v;
            }
        #pragma unroll
        for (int i = 0; i < 4; i++)
            #pragma unroll
            for (int m = 1; m < 16; m <<= 1) { sm2[i] += __shfl_xor(sm2[i], m, 64); sq2[i] += __shfl_xor(sq2[i], m, 64); }
        float mean2[4], rs2[4];
        #pragma unroll
        for (int i = 0; i < 4; i++) {
            mean2[i] = sm2[i] * (1.f / 128.f);
            float var = fmaxf(sq2[i] * (1.f / 128.f) - mean2[i] * mean2[i], 0.f);
            rs2[i] = rsqrtf(var + EPS_LN);
        }
        if (!do_pool) {
            u16* h2b = h2_out + (size_t)n0 * 128;
            #pragma unroll
            for (int t2 = 0; t2 < 8; t2++)
                #pragma unroll
                for (int i = 0; i < 4; i++) {
                    int col = t2 * 16 + c, idx = (q * 4 + i) * 128 + col;
                    float v = vout[t2][i];
                    hb[idx] = v;                                  // residual for next layer
                    float o = sP[896 + col] * (v - mean2[i]) * rs2[i] + sP[1024 + col];
                    h2b[idx] = f2bf(fmaxf(o, 0.f));               // next conv input
                }
        } else {
            int bg[4];
            #pragma unroll
            for (int i = 0; i < 4; i++) bg[i] = batch[n0 + q * 4 + i];
            #pragma unroll
            for (int t2 = 0; t2 < 8; t2++)
                #pragma unroll
                for (int i = 0; i < 4; i++) {
                    int col = t2 * 16 + c;
                    float o = sP[896 + col] * (vout[t2][i] - mean2[i]) * rs2[i] + sP[1024 + col];
                    unsafeAtomicAdd(&pool[(size_t)bg[i] * 128 + col], o);
                }
            if (c == 0)
                #pragma unroll
                for (int i = 0; i < 4; i++) unsafeAtomicAdd(&cnt[bg[i]], 1.f);
        }
    }
}

// =============== readout: sigmoid(mean_pool @ Wp + bp) ===============
__global__ __launch_bounds__(64) void k_read(const float* __restrict__ pool,
                                             const float* __restrict__ cnt,
                                             const float* __restrict__ Wp,
                                             const float* __restrict__ bp,
                                             float* __restrict__ out) {
    int g = blockIdx.x, lane = threadIdx.x;
    float inv = 1.f / fmaxf(cnt[g], 1.f);
    float d = (pool[(size_t)g * 128 + lane] * Wp[lane] +
               pool[(size_t)g * 128 + 64 + lane] * Wp[64 + lane]) * inv;
    float s = wave_sum(d);
    if (lane == 0) out[g] = 1.f / (1.f + expf(-(s + bp[0])));
}

extern "C" void kernel_launch(void* const* d_in, const int* in_sizes, int n_in,
                              void* d_out, int out_size, void* d_ws, size_t ws_size,
                              hipStream_t stream) {
    const float* x   = (const float*)d_in[0];
    const int*   ei  = (const int*)d_in[1];
    const int*   ea  = (const int*)d_in[2];
    const int*   bat = (const int*)d_in[3];
    const float* We  = (const float*)d_in[4];
    const float* be  = (const float*)d_in[5];
    const float* Et  = (const float*)d_in[6];
    const float* W1  = (const float*)d_in[7];
    const float* b1  = (const float*)d_in[8];
    const float* g1  = (const float*)d_in[9];
    const float* bb1 = (const float*)d_in[10];
    const float* W2  = (const float*)d_in[11];
    const float* b2  = (const float*)d_in[12];
    const float* gn  = (const float*)d_in[13];
    const float* bn  = (const float*)d_in[14];
    const float* Wp  = (const float*)d_in[15];
    const float* bp  = (const float*)d_in[16];
    float* out = (float*)d_out;

    char* w = (char*)d_ws;
    float* h    = (float*)w;  w += (size_t)N_NODES * 128 * 4;
    u16*   h2   = (u16*)w;    w += (size_t)N_NODES * 128 * 2;
    u16*   xin  = (u16*)w;    w += (size_t)N_NODES * 128 * 2;
    float* pool = (float*)w;  w += (size_t)NGRAPH * 128 * 4;
    float* cnt  = (float*)w;  w += (size_t)NGRAPH * 4;
    int*   deg  = (int*)w;    w += (size_t)N_NODES * 4;
    int*   offs = (int*)w;    w += (size_t)N_NODES * 4;
    int*   curs = (int*)w;    w += (size_t)N_NODES * 4;
    int*   bsum = (int*)w;    w += 128 * 4;
    int*   csr  = (int*)w;    w += (size_t)N_EDGES * 4;
    u16*   tW1  = (u16*)w;    w += (size_t)4 * 32768 * 2;
    u16*   tW2  = (u16*)w;    w += (size_t)4 * 32768 * 2;

    const int NB_SCAN = (N_NODES + 1023) / 1024;   // 98

    hipMemsetAsync(pool, 0, ((size_t)NGRAPH * 128 + NGRAPH) * 4, stream);
    hipMemsetAsync(deg, 0, (size_t)N_NODES * 4, stream);
    k_prep<<<512, 256, 0, stream>>>(W1, W2, tW1, tW2);
    // CSR build (edges are static across layers — build once per launch)
    k_hist<<<(N_EDGES + 255) / 256, 256, 0, stream>>>(ei, deg);
    k_scan1<<<NB_SCAN, 256, 0, stream>>>(deg, offs, bsum);
    k_scan2<<<1, 128, 0, stream>>>(bsum, NB_SCAN);
    k_scan3<<<NB_SCAN, 256, 0, stream>>>(offs, bsum, curs);
    k_scatter<<<(N_EDGES + 255) / 256, 256, 0, stream>>>(ei, ea, curs, csr);

    k_enc<<<256, 256, 0, stream>>>(x, We, be, h2);
    for (int l = 0; l < 4; l++) {
        k_agg<<<(N_NODES + 7) / 8, 256, 0, stream>>>(offs, deg, csr, Et, h2, xin);
        k_fused<<<256, 1024, 0, stream>>>(xin, h,
                                          tW1 + (size_t)l * 32768, b1 + l * 256,
                                          g1 + l * 256, bb1 + l * 256,
                                          tW2 + (size_t)l * 32768, b2 + l * 128,
                                          gn + l * 128, bn + l * 128,
                                          h2, bat, pool, cnt,
                                          l > 0 ? 1 : 0, l == 3 ? 1 : 0);
    }
    k_read<<<NGRAPH, 64, 0, stream>>>(pool, cnt, Wp, bp, out);
}